// Round 15
// baseline (67.290 us; speedup 1.0000x reference)
//
#include <hip/hip_runtime.h>
#include <hip/hip_fp16.h>

// NCC loss: two streaming passes + tiny reduce.
// K1 (ncc_hw): wave = (b,d,chunk); lanes = staggered w (56 outputs/wave).
//   Marches H (8 segs x 20 + 8 halo) with a 5ch x 9 f32 ring + running
//   window sums, packs to half2 and does the W 9-tap IN-WAVE on packed
//   fp16 (TAP9H), storing 10B/voxel: uint2 plane {(S0,S1),(S2,S3)} +
//   ushort plane {S4}.
// K2 (ncc_d): golden consumer, now 2 VOXELS PER THREAD: one uint4 (two
//   qA records) + one uint (two S4 ushorts = ready-made half2) per step
//   -> 2 load instrs per 20B (was 2 per 10B), dwordx4 coalescing, and the
//   S4 tree serves both voxels in one packed stream. Packed 9-slot rings
//   (45 uint regs), fp16 tree-sums, fp32 ncc, block reduce.
// K3: deterministic final reduction.

constexpr int BB = 2, DD = 160, HH = 160, WW = 160;
constexpr int SLICE = HH * WW;                         // 25600
constexpr long long NTOT = (long long)BB * DD * SLICE; // 8,192,000
constexpr int HSEG = 20, NHSEG = 8;                    // K1 h-segments
constexpr int DSEG = 20, NDSEG = 8;                    // K2 d-segments
constexpr int NPART = 100 * NDSEG;                     // 800 partials

static __device__ __forceinline__ unsigned pkh(float a, float b) {
  __half2 h = __floats2half2_rn(a, b);
  return __builtin_bit_cast(unsigned, h);
}
static __device__ __forceinline__ __half2 h2(unsigned u) {
  return __builtin_bit_cast(__half2, u);
}

// 9-tap in-wave box sum on packed __half2 (both halves independently):
// v[l] <- sum_{k=0..8} v[l+k]   (valid for lane <= 55)
#define TAP9H(v)                                                         \
  {                                                                      \
    unsigned _u = __builtin_bit_cast(unsigned, v);                       \
    __half2 _t1 = __builtin_bit_cast(__half2, __shfl_down(_u, 1, 64));   \
    __half2 _t2 = __builtin_bit_cast(__half2, __shfl_down(_u, 2, 64));   \
    v = v + _t1 + _t2;                                                   \
    _u = __builtin_bit_cast(unsigned, v);                                \
    __half2 _t3 = __builtin_bit_cast(__half2, __shfl_down(_u, 3, 64));   \
    __half2 _t6 = __builtin_bit_cast(__half2, __shfl_down(_u, 6, 64));   \
    v = v + _t3 + _t6;                                                   \
  }

// packed fp16 tree-sum of 9 ring slots (order-free)
#define SUM9(g) (((h2(g[0]) + h2(g[1])) + (h2(g[2]) + h2(g[3]))) +       \
                 ((h2(g[4]) + h2(g[5])) + (h2(g[6]) + h2(g[7]))) + h2(g[8]))

// ---------------- K1: H-ring + in-wave W-tap, 10B/voxel output ----------------
__global__ __launch_bounds__(256, 4) void ncc_hw_kernel(
    const float* __restrict__ f, const float* __restrict__ w,
    uint2* __restrict__ qA, ushort* __restrict__ qB) {
  const int tid = threadIdx.x;
  const int lane = tid & 63;
  const int wid = (blockIdx.x << 2) | (tid >> 6);  // 0..959 : (b,d,chunk)
  const int b = wid / 480;
  const int rem = wid % 480;
  const int d = rem / 3;
  const int ck = rem % 3;
  const int w_in = ck * 56 - 4 + lane;             // staggered input lane
  const int w_out = ck * 56 + lane;
  const bool vin = (unsigned)w_in < 160u;
  const bool vout = (lane < 56) && (w_out < 160);
  const int h0 = blockIdx.y * HSEG;
  const long long sb = (long long)(b * DD + d) * SLICE;
  const float* fr = f + sb + w_in;
  const float* wr = w + sb + w_in;

  float r0[9], r1[9], r2[9], r3[9], r4[9];
#pragma unroll
  for (int k = 0; k < 9; ++k) { r0[k] = r1[k] = r2[k] = r3[k] = r4[k] = 0.f; }
  float S0 = 0.f, S1 = 0.f, S2 = 0.f, S3 = 0.f, S4 = 0.f;

#pragma unroll
  for (int p = 0; p < HSEG + 8; ++p) {             // 28 steps
    const int j = h0 - 4 + p;                      // block-uniform guard
    float vf = 0.f, vw = 0.f;
    if ((unsigned)j < 160u && vin) {
      vf = fr[(long long)j * WW];
      vw = wr[(long long)j * WW];
    }
    const float a2 = vf * vf, a3 = vw * vw, a4 = vf * vw;
    const int sl = p % 9;                          // static after unroll
    S0 += vf - r0[sl]; r0[sl] = vf;
    S1 += vw - r1[sl]; r1[sl] = vw;
    S2 += a2 - r2[sl]; r2[sl] = a2;
    S3 += a3 - r3[sl]; r3[sl] = a3;
    S4 += a4 - r4[sl]; r4[sl] = a4;

    if (p >= 8) {
      __half2 z01 = h2(pkh(S0, S1));
      __half2 z23 = h2(pkh(S2, S3));
      __half2 z4x = h2(pkh(S4, 0.f));
      TAP9H(z01); TAP9H(z23); TAP9H(z4x);
      if (vout) {
        const long long rec = sb + (long long)(h0 + p - 8) * WW + w_out;
        qA[rec] = make_uint2(__builtin_bit_cast(unsigned, z01),
                             __builtin_bit_cast(unsigned, z23));
        qB[rec] = (ushort)(__builtin_bit_cast(unsigned, z4x) & 0xFFFFu);
      }
    }
  }
}

// ---------------- K2: D-march consumer, 2 voxels/thread ----------------
__global__ __launch_bounds__(256, 4) void ncc_d_kernel(
    const uint2* __restrict__ qA, const ushort* __restrict__ qB,
    float* __restrict__ partials) {
  const int tid = threadIdx.x;
  const int v0 = blockIdx.x * 512 + tid * 2;       // first of 2 voxels
  const int b = v0 / SLICE;                        // 512 | 25600: no straddle
  const int r = v0 % SLICE;
  const int d0 = blockIdx.y * DSEG;
  const long long base = (long long)b * DD * SLICE + r;   // even

  // packed 9-slice rings: 45 uint regs, static slots after full unroll
  unsigned a0[9], a1[9], b0[9], b1[9], c4[9];
#pragma unroll
  for (int k = 0; k < 9; ++k) { a0[k]=0u; a1[k]=0u; b0[k]=0u; b1[k]=0u; c4[k]=0u; }
  float acc = 0.f;
  const float inv = 1.0f / 729.0f;

#pragma unroll
  for (int p = 0; p < DSEG + 8; ++p) {             // 28 steps
    const int j = d0 - 4 + p;                      // block-uniform guard
    unsigned ua0 = 0u, ua1 = 0u, ub0 = 0u, ub1 = 0u, uc = 0u;
    if ((unsigned)j < 160u) {
      const long long i = base + (long long)j * SLICE;
      const uint4 uu = *reinterpret_cast<const uint4*>(qA + i);  // 2 records
      ua0 = uu.x; ua1 = uu.y;                      // voxel 0: ch01, ch23
      ub0 = uu.z; ub1 = uu.w;                      // voxel 1: ch01, ch23
      uc = *reinterpret_cast<const unsigned*>(qB + i);  // (S4_v0, S4_v1) half2
    }
    const int sl = p % 9;                          // static after unroll
    a0[sl] = ua0; a1[sl] = ua1; b0[sl] = ub0; b1[sl] = ub1; c4[sl] = uc;

    if (p >= 8) {
      const __half2 zA01 = SUM9(a0);
      const __half2 zA23 = SUM9(a1);
      const __half2 zB01 = SUM9(b0);
      const __half2 zB23 = SUM9(b1);
      const __half2 z4 = SUM9(c4);                 // lo = v0 S4, hi = v1 S4
      const float2 s4 = __half22float2(z4);
      // voxel 0
      {
        const float2 a01 = __half22float2(zA01);
        const float2 a23 = __half22float2(zA23);
        const float fm = a01.x * inv, wm = a01.y * inv;
        const float fv = a23.x * inv - fm * fm;
        const float wv = a23.y * inv - wm * wm;
        const float cov = s4.x * inv - fm * wm;
        const float den2 = (fmaxf(fv, 0.f) + 1e-8f) * (fmaxf(wv, 0.f) + 1e-8f);
        acc += fminf(1.f, fmaxf(-1.f, cov * rsqrtf(den2)));
      }
      // voxel 1
      {
        const float2 a01 = __half22float2(zB01);
        const float2 a23 = __half22float2(zB23);
        const float fm = a01.x * inv, wm = a01.y * inv;
        const float fv = a23.x * inv - fm * fm;
        const float wv = a23.y * inv - wm * wm;
        const float cov = s4.y * inv - fm * wm;
        const float den2 = (fmaxf(fv, 0.f) + 1e-8f) * (fmaxf(wv, 0.f) + 1e-8f);
        acc += fminf(1.f, fmaxf(-1.f, cov * rsqrtf(den2)));
      }
    }
  }

  __shared__ float red[256];
  red[tid] = acc;
  __syncthreads();
#pragma unroll
  for (int st = 128; st > 0; st >>= 1) {
    if (tid < st) red[tid] += red[tid + st];
    __syncthreads();
  }
  if (tid == 0) partials[blockIdx.y * gridDim.x + blockIdx.x] = red[0];
}

// ---------------- K3: final reduction ----------------
__global__ __launch_bounds__(1024) void ncc_final_kernel(
    const float* __restrict__ partials, float* __restrict__ out) {
  const int t = threadIdx.x;
  float a = 0.f;
  for (int i = t; i < NPART; i += 1024) a += partials[i];
#pragma unroll
  for (int off = 32; off > 0; off >>= 1) a += __shfl_down(a, off, 64);
  __shared__ float wr[16];
  if ((t & 63) == 0) wr[t >> 6] = a;
  __syncthreads();
  if (t == 0) {
    float s = 0.f;
#pragma unroll
    for (int k = 0; k < 16; ++k) s += wr[k];
    out[0] = -s * (1.0f / (float)NTOT);
  }
}

extern "C" void kernel_launch(void* const* d_in, const int* in_sizes, int n_in,
                              void* d_out, int out_size, void* d_ws, size_t ws_size,
                              hipStream_t stream) {
  const float* fixed = (const float*)d_in[0];
  const float* warped = (const float*)d_in[1];
  float* out = (float*)d_out;

  uint2* qA = (uint2*)d_ws;                                      // 65.54 MB
  ushort* qB = (ushort*)((char*)d_ws + (size_t)NTOT * 8);        // 16.38 MB
  float* partials = (float*)((char*)d_ws + (size_t)NTOT * 10);   // 3.2 KB

  dim3 g1(240, NHSEG);            // 960 waves x 8 h-segs = 1920 blocks
  ncc_hw_kernel<<<g1, dim3(256), 0, stream>>>(fixed, warped, qA, qB);

  dim3 g2(100, NDSEG);            // 800 blocks x 256 (2 voxels/thread)
  ncc_d_kernel<<<g2, dim3(256), 0, stream>>>(qA, qB, partials);

  ncc_final_kernel<<<1, dim3(1024), 0, stream>>>(partials, out);
}